// Round 6
// baseline (115.017 us; speedup 1.0000x reference)
//
#include <hip/hip_runtime.h>

// SelfAttentionPool, fused single kernel v5 (round 6).
// R1 49us -> R4 31 -> R5 26us (register-resident x_new, BT=512). Floor ~16.4.
// R5's residual: dot-phase cross-lane reduction = 70 LDS-pipe ops/thread
// (7 chunks x 5 shfl_xor x f64) serializing against edge staging + scatter
// atomics on the same LDS pipe.
// v5: 8 threads/row x 4 float4/thread (2 passes) -> per-row partials
// accumulate IN REGISTERS (3 f64 adds), one 3-step 8-lane xor tree remains.
// LDS-pipe ops in dot: ~560 -> ~48 wave-ops/block. Trade: wave loads touch
// 8x128B segments (2x requests, still coalesced); theta = 16 VGPRs.
// Numerics: identical f64 z pipeline as passing R1-R5 (order deltas ~1e-15).
//
// Output (float32): x_new (80000*128) | edge0 (E) | edge1 (E) | batch_new (80000)

#define NPG   100
#define EPG   1600
#define KNUM  80
#define FDIM  128
#define BT    512
#define NE4   (EPG / 4)          // 400 int4 per edge row

__device__ __forceinline__ double dot4d(float4 a, float4 t) {
    return (double)a.x * (double)t.x + (double)a.y * (double)t.y
         + (double)a.z * (double)t.z + (double)a.w * (double)t.w;
}

__global__ __launch_bounds__(BT)
void sagpool_fused5(const float* __restrict__ x,
                    const int*   __restrict__ ei,
                    const float* __restrict__ theta,
                    float* __restrict__ out,
                    int E_total, int out_x_elems)
{
    const int g    = blockIdx.x;
    const int tid  = threadIdx.x;
    const int wave = tid >> 6;
    const int lane = tid & 63;
    const int base = g * NPG;
    const int rj   = tid & 7;        // column-group within row (0..7)
    const int r0   = tid >> 3;       // row, pass 0 (0..63)
    const int r1   = 64 + r0;        // row, pass 1 (64..127)
    const bool act1 = r1 < NPG;      // tid < 288

    __shared__ int4   sh_edge4[NE4];              // packed: s | (d<<16)
    __shared__ int    sh_deg[NPG];
    __shared__ double sh_s[NPG];
    __shared__ double sh_dis[NPG];
    __shared__ double sh_a[NPG];                  // s * dis
    __shared__ double sh_zp[8][NPG];              // per-wave private scatter
    __shared__ double sh_z[NPG];
    __shared__ unsigned long long sh_mask[2];
    __shared__ int    sh_newid[NPG];              // global out row, or -1
    __shared__ float  sh_scalen[NPG];             // sigmoid(z), by node
    int* sh_edge = (int*)sh_edge4;

    if (tid < NPG) sh_deg[tid] = 1;               // self-loop
    for (int i = tid; i < 8 * NPG; i += BT) ((double*)sh_zp)[i] = 0.0;
    __syncthreads();                              // B1: deg/zp init

    // ---- issue edge loads first, then theta, then the x tile
    const int4* src4 = (const int4*)(ei + (size_t)g * EPG);
    const int4* dst4 = (const int4*)(ei + (size_t)E_total + (size_t)g * EPG);
    const bool  hasE = tid < NE4;
    int4 es, ed;
    if (hasE) { es = src4[tid]; ed = dst4[tid]; }

    const float4* th4 = (const float4*)theta;     // L1-broadcast, 512B total
    const float4 t0 = th4[rj];
    const float4 t1 = th4[rj + 8];
    const float4 t2 = th4[rj + 16];
    const float4 t3 = th4[rj + 24];

    const float4* xb4 = (const float4*)(x + (size_t)base * FDIM);
    const float4* xr0 = xb4 + (size_t)r0 * 32 + rj;
    float4 a0 = xr0[0], a1 = xr0[8], a2 = xr0[16], a3 = xr0[24];
    float4 b0, b1, b2, b3;
    if (act1) {
        const float4* xr1 = xb4 + (size_t)r1 * 32 + rj;
        b0 = xr1[0]; b1 = xr1[8]; b2 = xr1[16]; b3 = xr1[24];
    }

    // ---- edge pack + degree histogram (x loads still in flight)
    if (hasE) {
        int4 s4 = es, d4 = ed;
        s4.x -= base; s4.y -= base; s4.z -= base; s4.w -= base;
        d4.x -= base; d4.y -= base; d4.z -= base; d4.w -= base;
        int4 p; p.x = s4.x | (d4.x << 16); p.y = s4.y | (d4.y << 16);
                p.z = s4.z | (d4.z << 16); p.w = s4.w | (d4.w << 16);
        sh_edge4[tid] = p;
        atomicAdd(&sh_deg[s4.x], 1); atomicAdd(&sh_deg[s4.y], 1);
        atomicAdd(&sh_deg[s4.z], 1); atomicAdd(&sh_deg[s4.w], 1);
    }

    // ---- dot: per-row in-register accumulation + 3-step 8-lane xor tree
    {
        double p = dot4d(a0, t0) + dot4d(a1, t1) + dot4d(a2, t2) + dot4d(a3, t3);
        p += __shfl_xor(p, 1, 64);
        p += __shfl_xor(p, 2, 64);
        p += __shfl_xor(p, 4, 64);
        if (rj == 0) sh_s[r0] = p;
    }
    if (act1) {
        double p = dot4d(b0, t0) + dot4d(b1, t1) + dot4d(b2, t2) + dot4d(b3, t3);
        p += __shfl_xor(p, 1, 64);
        p += __shfl_xor(p, 2, 64);
        p += __shfl_xor(p, 4, 64);
        if (rj == 0) sh_s[r1] = p;
    }
    __syncthreads();                              // B2: edges, deg, s ready

    if (tid < NPG) {
        double dis = 1.0 / sqrt((double)sh_deg[tid]);
        sh_dis[tid] = dis;
        sh_a[tid]   = sh_s[tid] * dis;
    }
    __syncthreads();                              // B3: dis/a ready

    // ---- z scatter into per-wave private arrays (f64 LDS atomics)
    {
        double* zp = sh_zp[wave];
        for (int j = tid; j < EPG; j += BT) {
            int p = sh_edge[j];
            int s = p & 0xffff;
            int d = p >> 16;
            atomicAdd(&zp[d], sh_a[s] * sh_dis[d]);
        }
    }
    __syncthreads();                              // B4: scatter done

    double zi = 0.0;
    if (tid < NPG) {
        zi = sh_a[tid] * sh_dis[tid]              // self-loop term
           + sh_zp[0][tid] + sh_zp[1][tid] + sh_zp[2][tid] + sh_zp[3][tid]
           + sh_zp[4][tid] + sh_zp[5][tid] + sh_zp[6][tid] + sh_zp[7][tid];
        sh_z[tid] = zi;
    }
    __syncthreads();                              // B5: z ready

    // ---- top-k by rank (tie-break: lower index wins)
    bool kept = false;
    if (tid < NPG) {
        int rank = 0;
        for (int j = 0; j < NPG; ++j) {
            double zj = sh_z[j];
            rank += (int)((zj > zi) | ((zj == zi) & (j < tid)));
        }
        kept = rank < KNUM;
        sh_newid[tid] = -1;
    }
    unsigned long long m = __ballot(kept);
    if (lane == 0 && wave < 2) sh_mask[wave] = m;
    __syncthreads();                              // masks + newid init

    if (kept) {
        int before = (wave == 0)
            ? __popcll(sh_mask[0] & ((1ull << lane) - 1ull))
            : __popcll(sh_mask[0]) + __popcll(sh_mask[1] & ((1ull << lane) - 1ull));
        int row = g * KNUM + before;
        sh_newid[tid]   = row;
        sh_scalen[tid]  = (float)(1.0 / (1.0 + exp(-zi)));
        out[(size_t)out_x_elems + 2 * (size_t)E_total + row] = (float)g; // batch_new
    }
    __syncthreads();                              // B6: newid/scalen ready

    // ---- x_new straight from the register-resident tile (no re-read)
    float4* outx = (float4*)out;
    {
        int nid = sh_newid[r0];
        if (nid >= 0) {
            float sc = sh_scalen[r0];
            float4* o = outx + (size_t)nid * 32 + rj;
            float4 w;
            w.x = a0.x*sc; w.y = a0.y*sc; w.z = a0.z*sc; w.w = a0.w*sc; o[0]  = w;
            w.x = a1.x*sc; w.y = a1.y*sc; w.z = a1.z*sc; w.w = a1.w*sc; o[8]  = w;
            w.x = a2.x*sc; w.y = a2.y*sc; w.z = a2.z*sc; w.w = a2.w*sc; o[16] = w;
            w.x = a3.x*sc; w.y = a3.y*sc; w.z = a3.z*sc; w.w = a3.w*sc; o[24] = w;
        }
    }
    if (act1) {
        int nid = sh_newid[r1];
        if (nid >= 0) {
            float sc = sh_scalen[r1];
            float4* o = outx + (size_t)nid * 32 + rj;
            float4 w;
            w.x = b0.x*sc; w.y = b0.y*sc; w.z = b0.z*sc; w.w = b0.w*sc; o[0]  = w;
            w.x = b1.x*sc; w.y = b1.y*sc; w.z = b1.z*sc; w.w = b1.w*sc; o[8]  = w;
            w.x = b2.x*sc; w.y = b2.y*sc; w.z = b2.z*sc; w.w = b2.w*sc; o[16] = w;
            w.x = b3.x*sc; w.y = b3.y*sc; w.z = b3.z*sc; w.w = b3.w*sc; o[24] = w;
        }
    }

    // ---- edge relabel, float4 stores
    float* e0 = out + out_x_elems;
    float* e1 = e0 + E_total;
    if (hasE) {
        int4 p = sh_edge4[tid];
        float4 o0, o1;
        {
            int s = p.x & 0xffff, d = p.x >> 16;
            int a = sh_newid[s], b = sh_newid[d];
            bool vv = (a >= 0) && (b >= 0);
            o0.x = vv ? (float)a : -1.0f; o1.x = vv ? (float)b : -1.0f;
        }
        {
            int s = p.y & 0xffff, d = p.y >> 16;
            int a = sh_newid[s], b = sh_newid[d];
            bool vv = (a >= 0) && (b >= 0);
            o0.y = vv ? (float)a : -1.0f; o1.y = vv ? (float)b : -1.0f;
        }
        {
            int s = p.z & 0xffff, d = p.z >> 16;
            int a = sh_newid[s], b = sh_newid[d];
            bool vv = (a >= 0) && (b >= 0);
            o0.z = vv ? (float)a : -1.0f; o1.z = vv ? (float)b : -1.0f;
        }
        {
            int s = p.w & 0xffff, d = p.w >> 16;
            int a = sh_newid[s], b = sh_newid[d];
            bool vv = (a >= 0) && (b >= 0);
            o0.w = vv ? (float)a : -1.0f; o1.w = vv ? (float)b : -1.0f;
        }
        ((float4*)e0)[(size_t)g * NE4 + tid] = o0;
        ((float4*)e1)[(size_t)g * NE4 + tid] = o1;
    }
}

extern "C" void kernel_launch(void* const* d_in, const int* in_sizes, int n_in,
                              void* d_out, int out_size, void* d_ws, size_t ws_size,
                              hipStream_t stream)
{
    const float* x     = (const float*)d_in[0];
    const int*   ei    = (const int*)d_in[1];
    const float* theta = (const float*)d_in[3];
    float* out = (float*)d_out;

    const int N = in_sizes[0] / FDIM;        // 100000
    const int E = in_sizes[1] / 2;           // 1600000
    const int B = N / NPG;                   // 1000
    const int out_x_elems = B * KNUM * FDIM; // 10,240,000

    sagpool_fused5<<<dim3(B), dim3(BT), 0, stream>>>(x, ei, theta, out, E, out_x_elems);
}